// Round 1
// baseline (10617.554 us; speedup 1.0000x reference)
//
#include <hip/hip_runtime.h>
#include <cmath>

#define BN 2048
#define TN 512
#define HN 256
#define ROWS 8   // batch rows per block; 2048/8 = 256 blocks = 1 per CU

__device__ __forceinline__ float sigf(float v) { return 1.0f / (1.0f + expf(-v)); }

// Repack W_hh [4H][H] (row-major, k = g*256+unit) into W4 so that the main
// kernel's per-thread dwordx4 load is coalesced across lanes:
//   W4[ (jc*4 + g)*1024 + unit*4 + ju ]  = W_hh[(g*256+unit)*256 + jc*4+ju]
__global__ void repack_whh(const float* __restrict__ Whh, float* __restrict__ W4) {
    int idx = blockIdx.x * blockDim.x + threadIdx.x;
    if (idx >= 4 * HN * HN) return;
    int k = idx / HN;            // 0..1023
    int j = idx - k * HN;        // 0..255
    int g = k >> 8;              // gate 0..3 (i,f,g,o)
    int unit = k & 255;          // hidden unit
    W4[(size_t)((j >> 2) * 4 + g) * (HN * 4) + unit * 4 + (j & 3)] = Whh[idx];
}

template <bool PACKED>
__global__ __launch_bounds__(256) void lstm_seq(
    const float* __restrict__ x,      // [B][T]
    const float* __restrict__ W_ih,   // [4H]
    const float* __restrict__ W4,     // packed weights (or null)
    const float* __restrict__ Whh,    // raw [4H][H] fallback
    const float* __restrict__ b_ih,   // [4H]
    const float* __restrict__ b_hh,   // [4H]
    const float* __restrict__ W_lin,  // [H]
    const float* __restrict__ b_lin,  // [1]
    float* __restrict__ out)          // [B][T]
{
    __shared__ __align__(16) float h_lds[ROWS][HN];   // 8 KiB
    __shared__ float x_lds[ROWS][TN];                 // 16 KiB
    __shared__ float partial[4][ROWS];

    const int tid = threadIdx.x;      // == hidden unit owned by this thread
    const int lane = tid & 63;
    const int wv_id = tid >> 6;
    const int brow0 = blockIdx.x * ROWS;

    // Stage this block's x rows into LDS (coalesced along T).
    for (int b = 0; b < ROWS; ++b)
        for (int t = tid; t < TN; t += 256)
            x_lds[b][t] = x[(size_t)(brow0 + b) * TN + t];

    for (int b = 0; b < ROWS; ++b) h_lds[b][tid] = 0.0f;

    float c[ROWS];
#pragma unroll
    for (int b = 0; b < ROWS; ++b) c[b] = 0.0f;

    float bias[4], wih[4];
#pragma unroll
    for (int g = 0; g < 4; ++g) {
        bias[g] = b_ih[g * HN + tid] + b_hh[g * HN + tid];
        wih[g]  = W_ih[g * HN + tid];
    }
    const float wlin = W_lin[tid];
    const float blin = b_lin[0];
    __syncthreads();

    for (int t = 0; t < TN; ++t) {
        // acc[b][g] accumulates gates[b][g*256 + tid]
        float acc[ROWS][4];
#pragma unroll
        for (int b = 0; b < ROWS; ++b) {
            float xv = x_lds[b][t];
#pragma unroll
            for (int g = 0; g < 4; ++g) acc[b][g] = bias[g] + xv * wih[g];
        }

        // K-loop: gates[b][k] += sum_j h[b][j] * W_hh[k][j]
#pragma unroll 4
        for (int jc = 0; jc < HN / 4; ++jc) {
            float4 wv[4];
            if (PACKED) {
#pragma unroll
                for (int g = 0; g < 4; ++g)
                    wv[g] = *reinterpret_cast<const float4*>(
                        &W4[(size_t)(jc * 4 + g) * (HN * 4) + tid * 4]);
            } else {
#pragma unroll
                for (int g = 0; g < 4; ++g)
                    wv[g] = *reinterpret_cast<const float4*>(
                        &Whh[(size_t)(g * HN + tid) * HN + jc * 4]);
            }
            float4 hv[ROWS];
#pragma unroll
            for (int b = 0; b < ROWS; ++b)
                hv[b] = *reinterpret_cast<const float4*>(&h_lds[b][jc * 4]);
#pragma unroll
            for (int b = 0; b < ROWS; ++b) {
#pragma unroll
                for (int g = 0; g < 4; ++g) {
                    acc[b][g] += hv[b].x * wv[g].x;
                    acc[b][g] += hv[b].y * wv[g].y;
                    acc[b][g] += hv[b].z * wv[g].z;
                    acc[b][g] += hv[b].w * wv[g].w;
                }
            }
        }
        __syncthreads();  // all K-loop reads of h_lds complete

        float outc[ROWS];
#pragma unroll
        for (int b = 0; b < ROWS; ++b) {
            float gi = sigf(acc[b][0]);
            float gf = sigf(acc[b][1]);
            float gg = tanhf(acc[b][2]);
            float go = sigf(acc[b][3]);
            c[b] = gf * c[b] + gi * gg;
            float hn = go * tanhf(c[b]);
            h_lds[b][tid] = hn;
            outc[b] = hn * wlin;
        }

        // out[b][t] = sum_units h_new[b][unit]*W_lin[unit] + b_lin
#pragma unroll
        for (int b = 0; b < ROWS; ++b) {
            float v = outc[b];
#pragma unroll
            for (int m = 32; m >= 1; m >>= 1) v += __shfl_xor(v, m, 64);
            if (lane == 0) partial[wv_id][b] = v;
        }
        __syncthreads();  // h writes + partials visible
        if (tid < ROWS) {
            float v = partial[0][tid] + partial[1][tid] + partial[2][tid] +
                      partial[3][tid] + blin;
            out[(size_t)(brow0 + tid) * TN + t] = v;
        }
    }
}

extern "C" void kernel_launch(void* const* d_in, const int* in_sizes, int n_in,
                              void* d_out, int out_size, void* d_ws, size_t ws_size,
                              hipStream_t stream) {
    const float* x     = (const float*)d_in[0];
    const float* W_ih  = (const float*)d_in[1];
    const float* W_hh  = (const float*)d_in[2];
    const float* b_ih  = (const float*)d_in[3];
    const float* b_hh  = (const float*)d_in[4];
    const float* W_lin = (const float*)d_in[5];
    const float* b_lin = (const float*)d_in[6];
    float* out = (float*)d_out;

    const size_t packBytes = (size_t)4 * HN * HN * sizeof(float);  // 1 MiB
    if (ws_size >= packBytes) {
        float* W4 = (float*)d_ws;
        repack_whh<<<(4 * HN * HN + 255) / 256, 256, 0, stream>>>(W_hh, W4);
        lstm_seq<true><<<BN / ROWS, 256, 0, stream>>>(
            x, W_ih, W4, W_hh, b_ih, b_hh, W_lin, b_lin, out);
    } else {
        lstm_seq<false><<<BN / ROWS, 256, 0, stream>>>(
            x, W_ih, nullptr, W_hh, b_ih, b_hh, W_lin, b_lin, out);
    }
}

// Round 2
// 7539.458 us; speedup vs baseline: 1.4083x; 1.4083x over previous
//
#include <hip/hip_runtime.h>
#include <cmath>

#define BN 2048
#define TN 512
#define HN 256
#define ROWS 16
#define WAVES 8
#define THREADS (WAVES * 64)
#define NBLK (BN / ROWS)  // 128

typedef _Float16 half_t;
typedef _Float16 f16x8 __attribute__((ext_vector_type(8)));
typedef float f32x4 __attribute__((ext_vector_type(4)));

__device__ __forceinline__ float sigf(float v) {
    return __builtin_amdgcn_rcpf(1.0f + __expf(-v));
}
__device__ __forceinline__ float tanhf_fast(float v) {
    // tanh(x) = 1 - 2/(1+exp(2x)); saturates correctly for |x| large
    return 1.0f - 2.0f * __builtin_amdgcn_rcpf(1.0f + __expf(2.0f * v));
}

// Pack W_hh [4H][H] fp32 into fp16 MFMA B-fragment order.
// Global element idx bits: e[0:3) lane[3:9) kc[9:12) tile[12:15) w[15:18)
//   g = tile>>1, usub = tile&1
//   n = g*256 + 32*w + usub*16 + (lane&15)      (W_hh row; gate-major i,f,g,o)
//   k = kc*32 + (lane>>4)*8 + e                 (same k-map as A fragments)
__global__ void pack_w(const float* __restrict__ Whh, half_t* __restrict__ W4) {
    int idx = blockIdx.x * 256 + threadIdx.x;
    if (idx >= 4 * HN * HN) return;
    int e = idx & 7;
    int lane = (idx >> 3) & 63;
    int kc = (idx >> 9) & 7;
    int tile = (idx >> 12) & 7;
    int w = (idx >> 15) & 7;
    int g = tile >> 1, usub = tile & 1;
    int n = g * HN + 32 * w + usub * 16 + (lane & 15);
    int k = kc * 32 + (lane >> 4) * 8 + e;
    W4[idx] = (half_t)Whh[(size_t)n * HN + k];
}

template <bool PACKED>
__global__ __launch_bounds__(THREADS) void lstm_mfma(
    const float* __restrict__ x,      // [B][T]
    const float* __restrict__ W_ih,   // [4H]
    const half_t* __restrict__ W4,    // packed fp16 fragments (PACKED)
    const float* __restrict__ Whh,    // raw fallback
    const float* __restrict__ b_ih, const float* __restrict__ b_hh,
    const float* __restrict__ W_lin, const float* __restrict__ b_lin,
    float* __restrict__ out)          // [B][T]
{
    __shared__ float x_lds[ROWS][TN];                       // 32 KB
    __shared__ __align__(16) half_t h_lds[ROWS][HN + 8];    // pad 16B: stride 528B

    const int tid = threadIdx.x;
    const int lane = tid & 63;
    const int w = tid >> 6;
    const int li = lane & 15;
    const int lh = lane >> 4;  // 0..3
    const int brow0 = blockIdx.x * ROWS;

    for (int i = tid; i < ROWS * TN; i += THREADS) {
        int r = i >> 9, t = i & (TN - 1);
        x_lds[r][t] = x[(size_t)(brow0 + r) * TN + t];
    }
    for (int i = tid; i < ROWS * (HN + 8); i += THREADS)
        (&h_lds[0][0])[i] = (half_t)0.0f;

    // per-lane constants: this lane's 2 units (usub), 4 gates each
    float bias[2][4], wih[2][4];
#pragma unroll
    for (int usub = 0; usub < 2; ++usub) {
        int unit = 32 * w + usub * 16 + li;
#pragma unroll
        for (int g = 0; g < 4; ++g) {
            int n = g * HN + unit;
            bias[usub][g] = b_ih[n] + b_hh[n];
            wih[usub][g] = W_ih[n];
        }
    }
    float wl[8];
    {
        int c32 = tid & 31;
#pragma unroll
        for (int j = 0; j < 8; ++j) wl[j] = W_lin[c32 + 32 * j];
    }
    const float blin = b_lin[0];

    float c[2][4];
#pragma unroll
    for (int u = 0; u < 2; ++u)
#pragma unroll
        for (int r = 0; r < 4; ++r) c[u][r] = 0.0f;

    __syncthreads();

    const half_t* Wp = PACKED ? (W4 + ((size_t)w << 15)) : nullptr;

#define LOADB(BUF, KC)                                                          \
    do {                                                                        \
        if (PACKED) {                                                           \
            _Pragma("unroll") for (int tt = 0; tt < 8; ++tt)                    \
                BUF[tt] = *reinterpret_cast<const f16x8*>(                      \
                    Wp + (((tt * 8 + (KC)) << 9) + lane * 8));                  \
        } else {                                                                \
            _Pragma("unroll") for (int tt = 0; tt < 8; ++tt) {                  \
                int g_ = tt >> 1, us_ = tt & 1;                                 \
                int n_ = g_ * HN + 32 * w + us_ * 16 + li;                      \
                int k0_ = (KC) * 32 + lh * 8;                                   \
                const float* p_ = Whh + (size_t)n_ * HN + k0_;                  \
                float4 lo_ = *reinterpret_cast<const float4*>(p_);              \
                float4 hi_ = *reinterpret_cast<const float4*>(p_ + 4);          \
                f16x8 v_;                                                       \
                v_[0] = (half_t)lo_.x; v_[1] = (half_t)lo_.y;                   \
                v_[2] = (half_t)lo_.z; v_[3] = (half_t)lo_.w;                   \
                v_[4] = (half_t)hi_.x; v_[5] = (half_t)hi_.y;                   \
                v_[6] = (half_t)hi_.z; v_[7] = (half_t)hi_.w;                   \
                BUF[tt] = v_;                                                   \
            }                                                                   \
        }                                                                       \
    } while (0)

#define MFMA8(BUF, KC)                                                          \
    do {                                                                        \
        _Pragma("unroll") for (int tt = 0; tt < 8; ++tt)                        \
            acc[tt] = __builtin_amdgcn_mfma_f32_16x16x32_f16(a[KC], BUF[tt],    \
                                                             acc[tt], 0, 0, 0); \
    } while (0)

    for (int t = 0; t < TN; ++t) {
        // A fragments: h[m=li][k], k = kc*32 + lh*8 + e (same map as pack)
        f16x8 a[8];
#pragma unroll
        for (int kc = 0; kc < 8; ++kc)
            a[kc] = *reinterpret_cast<const f16x8*>(&h_lds[li][kc * 32 + lh * 8]);

        // acc init = bias + x_t * w_ih   (exact fp32 part of the gate)
        f32x4 acc[8];
#pragma unroll
        for (int tt = 0; tt < 8; ++tt) {
            int g = tt >> 1, usub = tt & 1;
#pragma unroll
            for (int r = 0; r < 4; ++r) {
                int m = lh * 4 + r;
                acc[tt][r] = bias[usub][g] + x_lds[m][t] * wih[usub][g];
            }
        }

        // K loop, depth-2/3 prefetch, fully unrolled
        f16x8 B0[8], B1[8], B2[8];
        LOADB(B0, 0); LOADB(B1, 1); LOADB(B2, 2);
        MFMA8(B0, 0); LOADB(B0, 3);
        MFMA8(B1, 1); LOADB(B1, 4);
        MFMA8(B2, 2); LOADB(B2, 5);
        MFMA8(B0, 3); LOADB(B0, 6);
        MFMA8(B1, 4); LOADB(B1, 7);
        MFMA8(B2, 5);
        MFMA8(B0, 6);
        MFMA8(B1, 7);

        // activations + state update (all fp32)
        float hnew[2][4];
#pragma unroll
        for (int usub = 0; usub < 2; ++usub) {
#pragma unroll
            for (int r = 0; r < 4; ++r) {
                float gi = sigf(acc[0 + usub][r]);
                float gf = sigf(acc[2 + usub][r]);
                float gg = tanhf_fast(acc[4 + usub][r]);
                float go = sigf(acc[6 + usub][r]);
                float cn = gf * c[usub][r] + gi * gg;
                c[usub][r] = cn;
                hnew[usub][r] = go * tanhf_fast(cn);
            }
        }

        __syncthreads();  // all reads of h_{t-1} (A-frags, out-proj) complete
#pragma unroll
        for (int usub = 0; usub < 2; ++usub) {
            int unit = 32 * w + usub * 16 + li;
#pragma unroll
            for (int r = 0; r < 4; ++r)
                h_lds[lh * 4 + r][unit] = (half_t)hnew[usub][r];
        }
        __syncthreads();  // h_t visible

        // out[b][t] = h_t @ W_lin + b_lin ; 32 threads per row
        {
            int row = tid >> 5, c32 = tid & 31;
            float s = 0.0f;
#pragma unroll
            for (int j = 0; j < 8; ++j)
                s += (float)h_lds[row][c32 + 32 * j] * wl[j];
#pragma unroll
            for (int m2 = 16; m2 >= 1; m2 >>= 1) s += __shfl_xor(s, m2, 64);
            if (c32 == 0) out[(size_t)(brow0 + row) * TN + t] = s + blin;
        }
    }
#undef LOADB
#undef MFMA8
}

extern "C" void kernel_launch(void* const* d_in, const int* in_sizes, int n_in,
                              void* d_out, int out_size, void* d_ws, size_t ws_size,
                              hipStream_t stream) {
    const float* x     = (const float*)d_in[0];
    const float* W_ih  = (const float*)d_in[1];
    const float* W_hh  = (const float*)d_in[2];
    const float* b_ih  = (const float*)d_in[3];
    const float* b_hh  = (const float*)d_in[4];
    const float* W_lin = (const float*)d_in[5];
    const float* b_lin = (const float*)d_in[6];
    float* out = (float*)d_out;

    const size_t packBytes = (size_t)4 * HN * HN * sizeof(half_t);  // 512 KB
    if (ws_size >= packBytes) {
        half_t* W4 = (half_t*)d_ws;
        pack_w<<<(4 * HN * HN + 255) / 256, 256, 0, stream>>>(W_hh, W4);
        lstm_mfma<true><<<NBLK, THREADS, 0, stream>>>(
            x, W_ih, W4, W_hh, b_ih, b_hh, W_lin, b_lin, out);
    } else {
        lstm_mfma<false><<<NBLK, THREADS, 0, stream>>>(
            x, W_ih, nullptr, W_hh, b_ih, b_hh, W_lin, b_lin, out);
    }
}

// Round 3
// 5506.541 us; speedup vs baseline: 1.9282x; 1.3692x over previous
//
#include <hip/hip_runtime.h>
#include <cmath>

#define BN 2048
#define TN 512
#define HN 256
#define ROWS 16
#define WAVES 16
#define THREADS 1024
#define NBLK (BN / ROWS)   // 128 blocks
#define HP (HN + 8)        // padded h row stride (f16): 528 B
#define XP (TN + 1)        // padded x row stride (f32)

typedef _Float16 half_t;
typedef _Float16 f16x8 __attribute__((ext_vector_type(8)));
typedef _Float16 f16x4 __attribute__((ext_vector_type(4)));
typedef float f32x4 __attribute__((ext_vector_type(4)));

__device__ __forceinline__ float sigf(float v) {
    return __builtin_amdgcn_rcpf(1.0f + __expf(-v));
}
__device__ __forceinline__ float tanhf_fast(float v) {
    return 1.0f - 2.0f * __builtin_amdgcn_rcpf(1.0f + __expf(2.0f * v));
}

// Pack W_hh [4H][H] fp32 -> fp16 B-fragment stream.
// idx bits: e[0:3) lane[3:9) kc[9:12) nt[12:14) w[14:18)
//   n = nt*256 + 16*w + (lane&15)   (gate-major col: i,f,g,o blocks of 256)
//   k = kc*32 + (lane>>4)*8 + e     (same k-map as A fragments)
__global__ void pack_w(const float* __restrict__ Whh, half_t* __restrict__ W4) {
    int idx = blockIdx.x * 256 + threadIdx.x;
    if (idx >= 4 * HN * HN) return;
    int e = idx & 7;
    int lane = (idx >> 3) & 63;
    int kc = (idx >> 9) & 7;
    int nt = (idx >> 12) & 3;
    int w = (idx >> 14) & 15;
    int n = nt * HN + 16 * w + (lane & 15);
    int k = kc * 32 + (lane >> 4) * 8 + e;
    W4[idx] = (half_t)Whh[(size_t)n * HN + k];
}

template <bool PACKED>
__global__ __launch_bounds__(THREADS, 4) void lstm_reg(
    const float* __restrict__ x,      // [B][T]
    const float* __restrict__ W_ih,   // [4H]
    const half_t* __restrict__ W4,    // packed fragments (PACKED)
    const float* __restrict__ Whh,    // raw fallback
    const float* __restrict__ b_ih, const float* __restrict__ b_hh,
    const float* __restrict__ W_lin, const float* __restrict__ b_lin,
    float* __restrict__ out)          // [B][T]
{
    __shared__ float x_lds[ROWS][XP];                     // ~32.1 KB
    __shared__ __align__(16) half_t h_lds[ROWS][HP];      // 8.25 KB

    const int tid = threadIdx.x;
    const int lane = tid & 63;
    const int w = tid >> 6;       // wave 0..15: owns units 16w..16w+15 (all gates) + out row w
    const int li = lane & 15;
    const int lh = lane >> 4;     // 0..3
    const int brow0 = blockIdx.x * ROWS;

    for (int i = tid; i < ROWS * TN; i += THREADS) {
        int r = i >> 9, t = i & (TN - 1);
        x_lds[r][t] = x[(size_t)(brow0 + r) * TN + t];
    }
    for (int i = tid; i < ROWS * HP; i += THREADS)
        (&h_lds[0][0])[i] = (half_t)0.0f;

    // ---- entire W_hh into registers: 32 fragments = 128 VGPRs/lane ----
    f16x8 Wr[4][8];
    if (PACKED) {
        const half_t* Wp = W4 + ((size_t)w << 14) + (size_t)lane * 8;
#pragma unroll
        for (int nt = 0; nt < 4; ++nt)
#pragma unroll
            for (int kc = 0; kc < 8; ++kc)
                Wr[nt][kc] = *reinterpret_cast<const f16x8*>(
                    Wp + (((nt << 3) + kc) << 9));
    } else {
#pragma unroll
        for (int nt = 0; nt < 4; ++nt) {
            int n = nt * HN + 16 * w + li;
#pragma unroll
            for (int kc = 0; kc < 8; ++kc) {
                const float* p = Whh + (size_t)n * HN + kc * 32 + lh * 8;
                float4 lo = *reinterpret_cast<const float4*>(p);
                float4 hi = *reinterpret_cast<const float4*>(p + 4);
                f16x8 v;
                v[0] = (half_t)lo.x; v[1] = (half_t)lo.y;
                v[2] = (half_t)lo.z; v[3] = (half_t)lo.w;
                v[4] = (half_t)hi.x; v[5] = (half_t)hi.y;
                v[6] = (half_t)hi.z; v[7] = (half_t)hi.w;
                Wr[nt][kc] = v;
            }
        }
    }

    // per-lane constants: this lane's unit (16w+li), 4 gates
    const int unit = 16 * w + li;
    float bias[4], wih[4];
#pragma unroll
    for (int g = 0; g < 4; ++g) {
        int n = g * HN + unit;
        bias[g] = b_ih[n] + b_hh[n];
        wih[g] = W_ih[n];
    }
    float wl[4];
#pragma unroll
    for (int j = 0; j < 4; ++j) wl[j] = W_lin[lane * 4 + j];
    const float blin = b_lin[0];

    float c[4];
#pragma unroll
    for (int r = 0; r < 4; ++r) c[r] = 0.0f;

    __syncthreads();

    for (int t = 0; t < TN; ++t) {
        // A fragments: h[m=li][k], k = kc*32 + lh*8 + e
        f16x8 a[8];
#pragma unroll
        for (int kc = 0; kc < 8; ++kc)
            a[kc] = *reinterpret_cast<const f16x8*>(&h_lds[li][kc * 32 + lh * 8]);

        // acc init = bias + x_t * w_ih (exact fp32 part)
        f32x4 acc[4];
#pragma unroll
        for (int nt = 0; nt < 4; ++nt)
#pragma unroll
            for (int r = 0; r < 4; ++r)
                acc[nt][r] = bias[nt] + x_lds[lh * 4 + r][t] * wih[nt];

        // 32 MFMAs, 4 independent chains (nt) round-robin
#pragma unroll
        for (int kc = 0; kc < 8; ++kc)
#pragma unroll
            for (int nt = 0; nt < 4; ++nt)
                acc[nt] = __builtin_amdgcn_mfma_f32_16x16x32_f16(
                    a[kc], Wr[nt][kc], acc[nt], 0, 0, 0);

        // activations + cell update (fp32), lane owns (rows lh*4+r, unit)
        float hnew[4];
#pragma unroll
        for (int r = 0; r < 4; ++r) {
            float gi = sigf(acc[0][r]);
            float gf = sigf(acc[1][r]);
            float gg = tanhf_fast(acc[2][r]);
            float go = sigf(acc[3][r]);
            float cn = gf * c[r] + gi * gg;
            c[r] = cn;
            hnew[r] = go * tanhf_fast(cn);
        }

        __syncthreads();  // all reads of h_{t-1} complete
#pragma unroll
        for (int r = 0; r < 4; ++r)
            h_lds[lh * 4 + r][unit] = (half_t)hnew[r];
        __syncthreads();  // h_t visible

        // out[brow0+w][t] = h_t[w] . W_lin + b_lin  (wave w owns row w)
        {
            f16x4 hv = *reinterpret_cast<const f16x4*>(&h_lds[w][lane * 4]);
            float s = (float)hv[0] * wl[0] + (float)hv[1] * wl[1] +
                      (float)hv[2] * wl[2] + (float)hv[3] * wl[3];
#pragma unroll
            for (int m2 = 32; m2 >= 1; m2 >>= 1) s += __shfl_xor(s, m2, 64);
            if (lane == 0) out[(size_t)(brow0 + w) * TN + t] = s + blin;
        }
    }
}

extern "C" void kernel_launch(void* const* d_in, const int* in_sizes, int n_in,
                              void* d_out, int out_size, void* d_ws, size_t ws_size,
                              hipStream_t stream) {
    const float* x     = (const float*)d_in[0];
    const float* W_ih  = (const float*)d_in[1];
    const float* W_hh  = (const float*)d_in[2];
    const float* b_ih  = (const float*)d_in[3];
    const float* b_hh  = (const float*)d_in[4];
    const float* W_lin = (const float*)d_in[5];
    const float* b_lin = (const float*)d_in[6];
    float* out = (float*)d_out;

    const size_t packBytes = (size_t)4 * HN * HN * sizeof(half_t);  // 512 KB
    if (ws_size >= packBytes) {
        half_t* W4 = (half_t*)d_ws;
        pack_w<<<(4 * HN * HN + 255) / 256, 256, 0, stream>>>(W_hh, W4);
        lstm_reg<true><<<NBLK, THREADS, 0, stream>>>(
            x, W_ih, W4, W_hh, b_ih, b_hh, W_lin, b_lin, out);
    } else {
        lstm_reg<false><<<NBLK, THREADS, 0, stream>>>(
            x, W_ih, nullptr, W_hh, b_ih, b_hh, W_lin, b_lin, out);
    }
}

// Round 4
// 1531.853 us; speedup vs baseline: 6.9312x; 3.5947x over previous
//
#include <hip/hip_runtime.h>
#include <cmath>

#define BN 2048
#define TN 512
#define HN 256
#define ROWS 8
#define WAVES 8
#define THREADS 512
#define NBLK (BN / ROWS)   // 256 blocks = 1 per CU
#define HP (HN + 8)        // padded h row: 528 B

typedef _Float16 half_t;
typedef _Float16 f16x8 __attribute__((ext_vector_type(8)));
typedef _Float16 f16x4 __attribute__((ext_vector_type(4)));
typedef float f32x4 __attribute__((ext_vector_type(4)));

__device__ __forceinline__ float sigf(float v) {
    return __builtin_amdgcn_rcpf(1.0f + __expf(-v));
}
__device__ __forceinline__ float tanhf_fast(float v) {
    return 1.0f - 2.0f * __builtin_amdgcn_rcpf(1.0f + __expf(2.0f * v));
}

// Pack W_hh [4H][H] fp32 -> fp16 fragment stream.
// idx bits: e[0:3) lane[3:9) kc[9:12) nt[12:15) w[15:18)
//   nt = u*4 + g  (u: 16-unit half, g: gate i,f,g,o)
//   n = g*256 + 32*w + u*16 + (lane&15)
//   k = kc*32 + (lane>>4)*8 + e        (same k-map as A fragments)
__global__ void pack_w(const float* __restrict__ Whh, half_t* __restrict__ W4) {
    int idx = blockIdx.x * 256 + threadIdx.x;
    if (idx >= 4 * HN * HN) return;
    int e = idx & 7;
    int lane = (idx >> 3) & 63;
    int kc = (idx >> 9) & 7;
    int nt = (idx >> 12) & 7;
    int w = (idx >> 15) & 7;
    int g = nt & 3, u = nt >> 2;
    int n = g * HN + 32 * w + u * 16 + (lane & 15);
    int k = kc * 32 + (lane >> 4) * 8 + e;
    W4[idx] = (half_t)Whh[(size_t)n * HN + k];
}

__device__ __forceinline__ f16x8 raw_frag(const float* __restrict__ Whh, int w,
                                          int g, int u, int kc, int li, int lh) {
    int n = g * HN + 32 * w + u * 16 + li;
    const float* p = Whh + (size_t)n * HN + kc * 32 + lh * 8;
    float4 lo = *reinterpret_cast<const float4*>(p);
    float4 hi = *reinterpret_cast<const float4*>(p + 4);
    f16x8 v;
    v[0] = (half_t)lo.x; v[1] = (half_t)lo.y;
    v[2] = (half_t)lo.z; v[3] = (half_t)lo.w;
    v[4] = (half_t)hi.x; v[5] = (half_t)hi.y;
    v[6] = (half_t)hi.z; v[7] = (half_t)hi.w;
    return v;
}

template <bool PACKED>
__global__ __launch_bounds__(THREADS, 2) void lstm_hot(
    const float* __restrict__ x,      // [B][T]
    const float* __restrict__ W_ih,   // [4H]
    const half_t* __restrict__ W4,    // packed fragments (PACKED)
    const float* __restrict__ Whh,    // raw fallback
    const float* __restrict__ b_ih, const float* __restrict__ b_hh,
    const float* __restrict__ W_lin, const float* __restrict__ b_lin,
    float* __restrict__ out)          // [B][T]
{
    __shared__ __align__(16) half_t ldsW[WAVES][2][8][512];  // 128 KB (g=3 tiles)
    __shared__ __align__(16) half_t h_lds[16][HP];           // 8.25 KB
    __shared__ float2 bw_lds[4 * HN];                        // 8 KB: {bias, w_ih}
    __shared__ float wl_lds[HN];                             // 1 KB

    const int tid = threadIdx.x;
    const int lane = tid & 63;
    const int w = tid >> 6;        // wave 0..7: units 32w..32w+31, out row w
    const int li = lane & 15;
    const int lh = lane >> 4;      // 0..3
    const int brow0 = blockIdx.x * ROWS;

    for (int i = tid; i < 4 * HN; i += THREADS)
        bw_lds[i] = make_float2(b_ih[i] + b_hh[i], W_ih[i]);
    for (int i = tid; i < HN; i += THREADS) wl_lds[i] = W_lin[i];
    for (int i = tid; i < 16 * HP; i += THREADS)
        (&h_lds[0][0])[i] = (half_t)0.0f;

    // ---- weights: gates 0..2 in VGPRs (192 regs), gate 3 in LDS ----
    f16x8 Wv[3][2][8];
    if (PACKED) {
        const half_t* Wb = W4 + ((size_t)w << 15) + lane * 8;
#pragma unroll
        for (int g = 0; g < 3; ++g)
#pragma unroll
            for (int u = 0; u < 2; ++u)
#pragma unroll
                for (int kc = 0; kc < 8; ++kc)
                    Wv[g][u][kc] = *reinterpret_cast<const f16x8*>(
                        Wb + (((u * 4 + g) << 12) | (kc << 9)));
#pragma unroll
        for (int u = 0; u < 2; ++u)
#pragma unroll
            for (int kc = 0; kc < 8; ++kc)
                *reinterpret_cast<f16x8*>(&ldsW[w][u][kc][lane * 8]) =
                    *reinterpret_cast<const f16x8*>(
                        Wb + (((u * 4 + 3) << 12) | (kc << 9)));
    } else {
#pragma unroll
        for (int g = 0; g < 3; ++g)
#pragma unroll
            for (int u = 0; u < 2; ++u)
#pragma unroll
                for (int kc = 0; kc < 8; ++kc)
                    Wv[g][u][kc] = raw_frag(Whh, w, g, u, kc, li, lh);
#pragma unroll
        for (int u = 0; u < 2; ++u)
#pragma unroll
            for (int kc = 0; kc < 8; ++kc)
                *reinterpret_cast<f16x8*>(&ldsW[w][u][kc][lane * 8]) =
                    raw_frag(Whh, w, 3, u, kc, li, lh);
    }

    // this lane's unit (after the fold) and row group
    const int unit = 32 * w + (lane >= 32 ? 16 : 0) + li;
    const int xbase = (lh & 1) * 4;  // rows xbase..xbase+3

    float c[4] = {0.0f, 0.0f, 0.0f, 0.0f};
    float xc[4], xn[4];
#pragma unroll
    for (int r = 0; r < 4; ++r)
        xc[r] = x[(size_t)(brow0 + xbase + r) * TN];
    const float blin = b_lin[0];

    __syncthreads();

    for (int t = 0; t < TN; ++t) {
        // prefetch next x (L1-resident after first pass)
        int tn = (t + 1 < TN) ? t + 1 : TN - 1;
#pragma unroll
        for (int r = 0; r < 4; ++r)
            xn[r] = x[(size_t)(brow0 + xbase + r) * TN + tn];

        float fold[4][4];
#pragma unroll
        for (int g = 0; g < 4; ++g) {
            f32x4 accA = {0.f, 0.f, 0.f, 0.f};
            f32x4 accB = {0.f, 0.f, 0.f, 0.f};
#pragma unroll
            for (int kc = 0; kc < 8; ++kc) {
                f16x8 a = *reinterpret_cast<const f16x8*>(
                    &h_lds[li][kc * 32 + lh * 8]);
                f16x8 bA, bB;
                if (g < 3) {
                    bA = Wv[g][0][kc];
                    bB = Wv[g][1][kc];
                } else {
                    bA = *reinterpret_cast<const f16x8*>(&ldsW[w][0][kc][lane * 8]);
                    bB = *reinterpret_cast<const f16x8*>(&ldsW[w][1][kc][lane * 8]);
                }
                accA = __builtin_amdgcn_mfma_f32_16x16x32_f16(a, bA, accA, 0, 0, 0);
                accB = __builtin_amdgcn_mfma_f32_16x16x32_f16(a, bB, accB, 0, 0, 0);
            }
            // fold: lanes<32 keep u0 (rows 0-7); lanes>=32 take u1 from lane-32
#pragma unroll
            for (int r = 0; r < 4; ++r) {
                float bsw = __shfl_xor(accB[r], 32, 64);
                fold[g][r] = (lane < 32) ? accA[r] : bsw;
            }
            // block LDS-load CSE across g-passes (keeps A-frags out of regs)
            asm volatile("" ::: "memory");
        }

        float2 bw[4];
#pragma unroll
        for (int g = 0; g < 4; ++g) bw[g] = bw_lds[g * HN + unit];

        float hnew[4];
#pragma unroll
        for (int r = 0; r < 4; ++r) {
            float gi = sigf(fold[0][r] + bw[0].x + xc[r] * bw[0].y);
            float gf = sigf(fold[1][r] + bw[1].x + xc[r] * bw[1].y);
            float gg = tanhf_fast(fold[2][r] + bw[2].x + xc[r] * bw[2].y);
            float go = sigf(fold[3][r] + bw[3].x + xc[r] * bw[3].y);
            float cn = gf * c[r] + gi * gg;
            c[r] = cn;
            hnew[r] = go * tanhf_fast(cn);
        }

        __syncthreads();  // all reads of h_{t-1} done
#pragma unroll
        for (int r = 0; r < 4; ++r)
            h_lds[xbase + r][unit] = (half_t)hnew[r];
        __syncthreads();  // h_t visible

        // out[brow0+w][t] = h_t[w] . W_lin + b_lin
        {
            f16x4 hv = *reinterpret_cast<const f16x4*>(&h_lds[w][lane * 4]);
            f32x4 wv = *reinterpret_cast<const f32x4*>(&wl_lds[lane * 4]);
            float s = (float)hv[0] * wv[0] + (float)hv[1] * wv[1] +
                      (float)hv[2] * wv[2] + (float)hv[3] * wv[3];
#pragma unroll
            for (int m2 = 32; m2 >= 1; m2 >>= 1) s += __shfl_xor(s, m2, 64);
            if (lane == 0) out[(size_t)(brow0 + w) * TN + t] = s + blin;
        }

#pragma unroll
        for (int r = 0; r < 4; ++r) xc[r] = xn[r];
    }
}

extern "C" void kernel_launch(void* const* d_in, const int* in_sizes, int n_in,
                              void* d_out, int out_size, void* d_ws, size_t ws_size,
                              hipStream_t stream) {
    const float* x     = (const float*)d_in[0];
    const float* W_ih  = (const float*)d_in[1];
    const float* W_hh  = (const float*)d_in[2];
    const float* b_ih  = (const float*)d_in[3];
    const float* b_hh  = (const float*)d_in[4];
    const float* W_lin = (const float*)d_in[5];
    const float* b_lin = (const float*)d_in[6];
    float* out = (float*)d_out;

    const size_t packBytes = (size_t)4 * HN * HN * sizeof(half_t);  // 512 KB
    if (ws_size >= packBytes) {
        half_t* W4 = (half_t*)d_ws;
        pack_w<<<(4 * HN * HN + 255) / 256, 256, 0, stream>>>(W_hh, W4);
        lstm_hot<true><<<NBLK, THREADS, 0, stream>>>(
            x, W_ih, W4, W_hh, b_ih, b_hh, W_lin, b_lin, out);
    } else {
        lstm_hot<false><<<NBLK, THREADS, 0, stream>>>(
            x, W_ih, nullptr, W_hh, b_ih, b_hh, W_lin, b_lin, out);
    }
}

// Round 5
// 1506.119 us; speedup vs baseline: 7.0496x; 1.0171x over previous
//
#include <hip/hip_runtime.h>
#include <cmath>

#define BN 2048
#define TN 512
#define HN 256
#define ROWS 8
#define WAVES 8
#define THREADS 512
#define NBLK (BN / ROWS)   // 256 blocks = 1 per CU
#define HP (HN + 8)        // padded h row: 528 B

typedef _Float16 half_t;
typedef _Float16 f16x8 __attribute__((ext_vector_type(8)));
typedef _Float16 f16x4 __attribute__((ext_vector_type(4)));
typedef float f32x4 __attribute__((ext_vector_type(4)));

__device__ __forceinline__ float sigf(float v) {
    return __builtin_amdgcn_rcpf(1.0f + __expf(-v));
}
__device__ __forceinline__ float tanhf_fast(float v) {
    return 1.0f - 2.0f * __builtin_amdgcn_rcpf(1.0f + __expf(2.0f * v));
}

// Pack W_hh [4H][H] fp32 -> fp16 fragment stream.
// idx bits: e[0:3) lane[3:9) kc[9:12) nt[12:15) w[15:18)
//   nt = u*4 + g  (u: 16-unit half, g: gate i,f,g,o)
//   n = g*256 + 32*w + u*16 + (lane&15)
//   k = kc*32 + (lane>>4)*8 + e        (same k-map as A fragments)
__global__ void pack_w(const float* __restrict__ Whh, half_t* __restrict__ W4) {
    int idx = blockIdx.x * 256 + threadIdx.x;
    if (idx >= 4 * HN * HN) return;
    int e = idx & 7;
    int lane = (idx >> 3) & 63;
    int kc = (idx >> 9) & 7;
    int nt = (idx >> 12) & 7;
    int w = (idx >> 15) & 7;
    int g = nt & 3, u = nt >> 2;
    int n = g * HN + 32 * w + u * 16 + (lane & 15);
    int k = kc * 32 + (lane >> 4) * 8 + e;
    W4[idx] = (half_t)Whh[(size_t)n * HN + k];
}

__device__ __forceinline__ f16x8 raw_frag(const float* __restrict__ Whh, int w,
                                          int g, int u, int kc, int li, int lh) {
    int n = g * HN + 32 * w + u * 16 + li;
    const float* p = Whh + (size_t)n * HN + kc * 32 + lh * 8;
    float4 lo = *reinterpret_cast<const float4*>(p);
    float4 hi = *reinterpret_cast<const float4*>(p + 4);
    f16x8 v;
    v[0] = (half_t)lo.x; v[1] = (half_t)lo.y;
    v[2] = (half_t)lo.z; v[3] = (half_t)lo.w;
    v[4] = (half_t)hi.x; v[5] = (half_t)hi.y;
    v[6] = (half_t)hi.z; v[7] = (half_t)hi.w;
    return v;
}

template <bool PACKED>
__global__ __launch_bounds__(THREADS, 2) void lstm_hot(
    const float* __restrict__ x,      // [B][T]
    const float* __restrict__ W_ih,   // [4H]
    const half_t* __restrict__ W4,    // packed fragments (PACKED)
    const float* __restrict__ Whh,    // raw fallback
    const float* __restrict__ b_ih, const float* __restrict__ b_hh,
    const float* __restrict__ W_lin, const float* __restrict__ b_lin,
    float* __restrict__ out)          // [B][T]
{
    __shared__ __align__(16) half_t ldsW[WAVES][2][8][512];  // 128 KB (gate-3 tiles)
    __shared__ __align__(16) half_t h_lds[2][16][HP];        // 16.5 KB double buffer
    __shared__ float2 bw_lds[4 * HN];                        // 8 KB: {bias, w_ih}
    __shared__ float wl_lds[HN];                             // 1 KB

    const int tid = threadIdx.x;
    const int lane = tid & 63;
    const int w = tid >> 6;        // wave 0..7: units 32w..32w+31, out row w
    const int li = lane & 15;
    const int lh = lane >> 4;      // 0..3
    const int brow0 = blockIdx.x * ROWS;

    for (int i = tid; i < 4 * HN; i += THREADS)
        bw_lds[i] = make_float2(b_ih[i] + b_hh[i], W_ih[i]);
    for (int i = tid; i < HN; i += THREADS) wl_lds[i] = W_lin[i];
    for (int i = tid; i < 2 * 16 * HP; i += THREADS)
        (&h_lds[0][0][0])[i] = (half_t)0.0f;

    // ---- weights: gates 0..2 in registers (192 regs), gate 3 in LDS ----
    f16x8 Wv[3][2][8];
    if (PACKED) {
        const half_t* Wb = W4 + ((size_t)w << 15) + lane * 8;
#pragma unroll
        for (int g = 0; g < 3; ++g)
#pragma unroll
            for (int u = 0; u < 2; ++u)
#pragma unroll
                for (int kc = 0; kc < 8; ++kc)
                    Wv[g][u][kc] = *reinterpret_cast<const f16x8*>(
                        Wb + (((u * 4 + g) << 12) | (kc << 9)));
#pragma unroll
        for (int u = 0; u < 2; ++u)
#pragma unroll
            for (int kc = 0; kc < 8; ++kc)
                *reinterpret_cast<f16x8*>(&ldsW[w][u][kc][lane * 8]) =
                    *reinterpret_cast<const f16x8*>(
                        Wb + (((u * 4 + 3) << 12) | (kc << 9)));
    } else {
#pragma unroll
        for (int g = 0; g < 3; ++g)
#pragma unroll
            for (int u = 0; u < 2; ++u)
#pragma unroll
                for (int kc = 0; kc < 8; ++kc)
                    Wv[g][u][kc] = raw_frag(Whh, w, g, u, kc, li, lh);
#pragma unroll
        for (int u = 0; u < 2; ++u)
#pragma unroll
            for (int kc = 0; kc < 8; ++kc)
                *reinterpret_cast<f16x8*>(&ldsW[w][u][kc][lane * 8]) =
                    raw_frag(Whh, w, 3, u, kc, li, lh);
    }

    // this lane's unit (after the fold) and row group
    const int unit = 32 * w + (lane >= 32 ? 16 : 0) + li;
    const int xbase = (lh & 1) * 4;  // rows xbase..xbase+3

    float c[4] = {0.0f, 0.0f, 0.0f, 0.0f};
    const float blin = b_lin[0];

    __syncthreads();

    for (int t = 0; t < TN; ++t) {
        const int p = t & 1;  // read buffer (h after step t-1; zeros at t=0)

        // x for this step (L1-resident after first sweep)
        float xr[4];
#pragma unroll
        for (int r = 0; r < 4; ++r)
            xr[r] = x[(size_t)(brow0 + xbase + r) * TN + t];

        // deferred output projection: out[t-1] = proj(h in buf[p])
        {
            f16x4 hv = *reinterpret_cast<const f16x4*>(&h_lds[p][w][lane * 4]);
            f32x4 wv = *reinterpret_cast<const f32x4*>(&wl_lds[lane * 4]);
            float s = (float)hv[0] * wv[0] + (float)hv[1] * wv[1] +
                      (float)hv[2] * wv[2] + (float)hv[3] * wv[3];
#pragma unroll
            for (int m2 = 32; m2 >= 1; m2 >>= 1) s += __shfl_xor(s, m2, 64);
            if (t > 0 && lane == 0)
                out[(size_t)(brow0 + w) * TN + (t - 1)] = s + blin;
        }

        // gates: 8 independent MFMA chains (4 gates x 2 u), A loaded once per kc
        f32x4 acc[4][2];
#pragma unroll
        for (int g = 0; g < 4; ++g)
#pragma unroll
            for (int u = 0; u < 2; ++u)
                acc[g][u] = f32x4{0.f, 0.f, 0.f, 0.f};

#pragma unroll
        for (int kc = 0; kc < 8; ++kc) {
            f16x8 a = *reinterpret_cast<const f16x8*>(
                &h_lds[p][li][kc * 32 + lh * 8]);
            f16x8 b3u0 = *reinterpret_cast<const f16x8*>(&ldsW[w][0][kc][lane * 8]);
            f16x8 b3u1 = *reinterpret_cast<const f16x8*>(&ldsW[w][1][kc][lane * 8]);
#pragma unroll
            for (int g = 0; g < 3; ++g) {
                acc[g][0] = __builtin_amdgcn_mfma_f32_16x16x32_f16(
                    a, Wv[g][0][kc], acc[g][0], 0, 0, 0);
                acc[g][1] = __builtin_amdgcn_mfma_f32_16x16x32_f16(
                    a, Wv[g][1][kc], acc[g][1], 0, 0, 0);
            }
            acc[3][0] = __builtin_amdgcn_mfma_f32_16x16x32_f16(a, b3u0, acc[3][0], 0, 0, 0);
            acc[3][1] = __builtin_amdgcn_mfma_f32_16x16x32_f16(a, b3u1, acc[3][1], 0, 0, 0);
        }

        // fold u0/u1 across lane halves, then activations (identical math to R4)
        float2 bw[4];
#pragma unroll
        for (int g = 0; g < 4; ++g) bw[g] = bw_lds[g * HN + unit];

        float hnew[4];
#pragma unroll
        for (int r = 0; r < 4; ++r) {
            float f0 = (lane < 32) ? acc[0][0][r] : 0.f;
            float f1 = (lane < 32) ? acc[1][0][r] : 0.f;
            float f2 = (lane < 32) ? acc[2][0][r] : 0.f;
            float f3 = (lane < 32) ? acc[3][0][r] : 0.f;
            float s0 = __shfl_xor(acc[0][1][r], 32, 64);
            float s1 = __shfl_xor(acc[1][1][r], 32, 64);
            float s2 = __shfl_xor(acc[2][1][r], 32, 64);
            float s3 = __shfl_xor(acc[3][1][r], 32, 64);
            if (lane >= 32) { f0 = s0; f1 = s1; f2 = s2; f3 = s3; }
            float gi = sigf(f0 + bw[0].x + xr[r] * bw[0].y);
            float gf = sigf(f1 + bw[1].x + xr[r] * bw[1].y);
            float gg = tanhf_fast(f2 + bw[2].x + xr[r] * bw[2].y);
            float go = sigf(f3 + bw[3].x + xr[r] * bw[3].y);
            float cn = gf * c[r] + gi * gg;
            c[r] = cn;
            hnew[r] = go * tanhf_fast(cn);
        }

        // write h_t into the other buffer (rows 0..7 only; 8..15 stay zero)
#pragma unroll
        for (int r = 0; r < 4; ++r)
            h_lds[1 - p][xbase + r][unit] = (half_t)hnew[r];

        __syncthreads();  // h_t visible; also fences next iter's overwrites
    }

    // epilogue: out[T-1] from final h (in buf[TN & 1 ^ ... ] = buf[TN&1? ]):
    // last iter t=TN-1 wrote buf[(TN-1+1)&1] = buf[TN&1] = buf[0]
    {
        const int pf = TN & 1;  // = 0
        f16x4 hv = *reinterpret_cast<const f16x4*>(&h_lds[pf][w][lane * 4]);
        f32x4 wv = *reinterpret_cast<const f32x4*>(&wl_lds[lane * 4]);
        float s = (float)hv[0] * wv[0] + (float)hv[1] * wv[1] +
                  (float)hv[2] * wv[2] + (float)hv[3] * wv[3];
#pragma unroll
        for (int m2 = 32; m2 >= 1; m2 >>= 1) s += __shfl_xor(s, m2, 64);
        if (lane == 0)
            out[(size_t)(brow0 + w) * TN + (TN - 1)] = s + blin;
    }
}

extern "C" void kernel_launch(void* const* d_in, const int* in_sizes, int n_in,
                              void* d_out, int out_size, void* d_ws, size_t ws_size,
                              hipStream_t stream) {
    const float* x     = (const float*)d_in[0];
    const float* W_ih  = (const float*)d_in[1];
    const float* W_hh  = (const float*)d_in[2];
    const float* b_ih  = (const float*)d_in[3];
    const float* b_hh  = (const float*)d_in[4];
    const float* W_lin = (const float*)d_in[5];
    const float* b_lin = (const float*)d_in[6];
    float* out = (float*)d_out;

    const size_t packBytes = (size_t)4 * HN * HN * sizeof(half_t);  // 512 KB
    if (ws_size >= packBytes) {
        half_t* W4 = (half_t*)d_ws;
        pack_w<<<(4 * HN * HN + 255) / 256, 256, 0, stream>>>(W_hh, W4);
        lstm_hot<true><<<NBLK, THREADS, 0, stream>>>(
            x, W_ih, W4, W_hh, b_ih, b_hh, W_lin, b_lin, out);
    } else {
        lstm_hot<false><<<NBLK, THREADS, 0, stream>>>(
            x, W_ih, nullptr, W_hh, b_ih, b_hh, W_lin, b_lin, out);
    }
}

// Round 9
// 1254.059 us; speedup vs baseline: 8.4666x; 1.2010x over previous
//
#include <hip/hip_runtime.h>
#include <cmath>

#define BN 2048
#define TN 512
#define HN 256
#define ROWS 8
#define WAVES 8
#define THREADS 512
#define NBLK (BN / ROWS)   // 256 blocks = 1 per CU
#define HP (HN + 8)        // padded h row: 528 B

typedef _Float16 half_t;
typedef _Float16 f16x8 __attribute__((ext_vector_type(8)));
typedef _Float16 f16x4 __attribute__((ext_vector_type(4)));
typedef float f32x4 __attribute__((ext_vector_type(4)));

__device__ __forceinline__ float sigf(float v) {
    return __builtin_amdgcn_rcpf(1.0f + __expf(-v));
}
__device__ __forceinline__ float tanhf_fast(float v) {
    return 1.0f - 2.0f * __builtin_amdgcn_rcpf(1.0f + __expf(2.0f * v));
}

// Pack W_hh [4H][H] fp32 -> fp16 fragment stream (UNSCALED — R5 numerics).
// idx bits: e[0:3) lane[3:9) kc[9:12) nt[12:15) w[15:18)
//   nt = u*4 + g; n = g*256 + 32*w + u*16 + (lane&15); k = kc*32+(lane>>4)*8+e
__global__ void pack_w(const float* __restrict__ Whh, half_t* __restrict__ W4) {
    int idx = blockIdx.x * 256 + threadIdx.x;
    if (idx >= 4 * HN * HN) return;
    int e = idx & 7;
    int lane = (idx >> 3) & 63;
    int kc = (idx >> 9) & 7;
    int nt = (idx >> 12) & 7;
    int w = (idx >> 15) & 7;
    int g = nt & 3, u = nt >> 2;
    int n = g * HN + 32 * w + u * 16 + (lane & 15);
    int k = kc * 32 + (lane >> 4) * 8 + e;
    W4[idx] = (half_t)Whh[(size_t)n * HN + k];
}

__device__ __forceinline__ f16x8 raw_frag(const float* __restrict__ Whh, int w,
                                          int g, int u, int kc, int li, int lh) {
    int n = g * HN + 32 * w + u * 16 + li;
    const float* p = Whh + (size_t)n * HN + kc * 32 + lh * 8;
    float4 lo = *reinterpret_cast<const float4*>(p);
    float4 hi = *reinterpret_cast<const float4*>(p + 4);
    f16x8 v;
    v[0] = (half_t)lo.x; v[1] = (half_t)lo.y;
    v[2] = (half_t)lo.z; v[3] = (half_t)lo.w;
    v[4] = (half_t)hi.x; v[5] = (half_t)hi.y;
    v[6] = (half_t)hi.z; v[7] = (half_t)hi.w;
    return v;
}

template <bool PACKED>
__global__ __launch_bounds__(THREADS, 2) void lstm_hot(
    const float* __restrict__ x,      // [B][T]
    const float* __restrict__ W_ih,   // [4H]
    const half_t* __restrict__ W4,    // packed fragments (PACKED)
    const float* __restrict__ Whh,    // raw fallback
    const float* __restrict__ b_ih, const float* __restrict__ b_hh,
    const float* __restrict__ W_lin, const float* __restrict__ b_lin,
    float* __restrict__ out)          // [B][T]
{
    __shared__ __align__(16) half_t ldsW[WAVES][2][8][512];  // 128 KB (gate-3)
    __shared__ __align__(16) half_t h_lds[2][16][HP];        // 16.5 KB dbuf
    __shared__ float2 bw_lds[4 * HN];                        // 8 KB {bias, w_ih}
    __shared__ float wl_lds[HN];                             // 1 KB

    const int tid = threadIdx.x;
    const int lane = tid & 63;
    const int w = tid >> 6;        // wave w: units 32w..32w+31, out row w
    const int li = lane & 15;
    const int lh = lane >> 4;      // 0..3
    const int brow0 = blockIdx.x * ROWS;

    for (int i = tid; i < 4 * HN; i += THREADS)
        bw_lds[i] = make_float2(b_ih[i] + b_hh[i], W_ih[i]);
    for (int i = tid; i < HN; i += THREADS) wl_lds[i] = W_lin[i];
    for (int i = tid; i < 2 * 16 * HP; i += THREADS)
        (&h_lds[0][0][0])[i] = (half_t)0.0f;

    // ---- weights: gates 0..2 in registers/AGPRs (192), gate 3 in LDS ----
    f16x8 Wv[3][2][8];
    if (PACKED) {
        const half_t* Wb = W4 + ((size_t)w << 15) + lane * 8;
#pragma unroll
        for (int g = 0; g < 3; ++g)
#pragma unroll
            for (int u = 0; u < 2; ++u)
#pragma unroll
                for (int kc = 0; kc < 8; ++kc)
                    Wv[g][u][kc] = *reinterpret_cast<const f16x8*>(
                        Wb + (((u * 4 + g) << 12) | (kc << 9)));
#pragma unroll
        for (int u = 0; u < 2; ++u)
#pragma unroll
            for (int kc = 0; kc < 8; ++kc)
                *reinterpret_cast<f16x8*>(&ldsW[w][u][kc][lane * 8]) =
                    *reinterpret_cast<const f16x8*>(
                        Wb + (((u * 4 + 3) << 12) | (kc << 9)));
    } else {
#pragma unroll
        for (int g = 0; g < 3; ++g)
#pragma unroll
            for (int u = 0; u < 2; ++u)
#pragma unroll
                for (int kc = 0; kc < 8; ++kc)
                    Wv[g][u][kc] = raw_frag(Whh, w, g, u, kc, li, lh);
#pragma unroll
        for (int u = 0; u < 2; ++u)
#pragma unroll
            for (int kc = 0; kc < 8; ++kc)
                *reinterpret_cast<f16x8*>(&ldsW[w][u][kc][lane * 8]) =
                    raw_frag(Whh, w, 3, u, kc, li, lh);
    }

    const int unit = 32 * w + (lane >= 32 ? 16 : 0) + li;
    const int xbase = (lh & 1) * 4;  // rows xbase..xbase+3
    const float* xptr = x + (size_t)(brow0 + xbase) * TN;

    float c[4] = {0.0f, 0.0f, 0.0f, 0.0f};
    const float blin = b_lin[0];
    float ov = 0.0f;  // out[w][·]: lane s holds out value for step (blk*64+s)

    __syncthreads();

    for (int t = 0; t < TN; ++t) {
        const int p = t & 1;  // buffer holding h_{t-1}

        // x for this step (issued early; L1-resident after first sweep)
        float xr[4];
#pragma unroll
        for (int r = 0; r < 4; ++r) xr[r] = xptr[(size_t)r * TN + t];

        // projection of h_{t-1} (row w) -> ov slot (t-1)&63; flush /64 steps.
        {
            f16x4 hv = *reinterpret_cast<const f16x4*>(&h_lds[p][w][lane * 4]);
            f32x4 wv = *reinterpret_cast<const f32x4*>(&wl_lds[lane * 4]);
            float s = (float)hv[0] * wv[0] + (float)hv[1] * wv[1] +
                      (float)hv[2] * wv[2] + (float)hv[3] * wv[3];
#pragma unroll
            for (int m2 = 32; m2 >= 1; m2 >>= 1) s += __shfl_xor(s, m2, 64);
            float val = s + blin;
            ov = (((t - 1) & 63) == lane) ? val : ov;
            if ((t & 63) == 0 && t > 0)
                out[(size_t)(brow0 + w) * TN + (t - 64) + lane] = ov;
        }

        // gates: 8 independent MFMA chains, A loaded once per kc
        f32x4 acc[4][2];
#pragma unroll
        for (int g = 0; g < 4; ++g)
#pragma unroll
            for (int u = 0; u < 2; ++u)
                acc[g][u] = f32x4{0.f, 0.f, 0.f, 0.f};

#pragma unroll
        for (int kc = 0; kc < 8; ++kc) {
            f16x8 a = *reinterpret_cast<const f16x8*>(
                &h_lds[p][li][kc * 32 + lh * 8]);
            f16x8 b3u0 = *reinterpret_cast<const f16x8*>(&ldsW[w][0][kc][lane * 8]);
            f16x8 b3u1 = *reinterpret_cast<const f16x8*>(&ldsW[w][1][kc][lane * 8]);
#pragma unroll
            for (int g = 0; g < 3; ++g) {
                acc[g][0] = __builtin_amdgcn_mfma_f32_16x16x32_f16(
                    a, Wv[g][0][kc], acc[g][0], 0, 0, 0);
                acc[g][1] = __builtin_amdgcn_mfma_f32_16x16x32_f16(
                    a, Wv[g][1][kc], acc[g][1], 0, 0, 0);
            }
            acc[3][0] = __builtin_amdgcn_mfma_f32_16x16x32_f16(a, b3u0, acc[3][0], 0, 0, 0);
            acc[3][1] = __builtin_amdgcn_mfma_f32_16x16x32_f16(a, b3u1, acc[3][1], 0, 0, 0);
        }

        // fold u0/u1 across lane halves (R5-proven shfl_xor + select):
        // lanes<32 keep u0 rows 0-7; lanes>=32 take u1 rows 0-7 from lane-32.
        float fold[4][4];
#pragma unroll
        for (int g = 0; g < 4; ++g)
#pragma unroll
            for (int r = 0; r < 4; ++r) {
                float a0 = (lane < 32) ? acc[g][0][r] : 0.f;
                float sw = __shfl_xor(acc[g][1][r], 32, 64);
                fold[g][r] = (lane >= 32) ? sw : a0;
            }

        float2 bw[4];
#pragma unroll
        for (int g = 0; g < 4; ++g) bw[g] = bw_lds[g * HN + unit];

        float hnew[4];
#pragma unroll
        for (int r = 0; r < 4; ++r) {
            float gi = sigf(fold[0][r] + bw[0].x + xr[r] * bw[0].y);
            float gf = sigf(fold[1][r] + bw[1].x + xr[r] * bw[1].y);
            float gg = tanhf_fast(fold[2][r] + bw[2].x + xr[r] * bw[2].y);
            float go = sigf(fold[3][r] + bw[3].x + xr[r] * bw[3].y);
            float cn = gf * c[r] + gi * gg;
            c[r] = cn;
            hnew[r] = go * tanhf_fast(cn);
        }

#pragma unroll
        for (int r = 0; r < 4; ++r)
            h_lds[1 - p][xbase + r][unit] = (half_t)hnew[r];

        __syncthreads();  // h_t visible (proven barrier; vmcnt drain now cheap)
    }

    // epilogue: out[511] from final h (buf[0]) + flush block 448..511
    {
        f16x4 hv = *reinterpret_cast<const f16x4*>(&h_lds[0][w][lane * 4]);
        f32x4 wv = *reinterpret_cast<const f32x4*>(&wl_lds[lane * 4]);
        float s = (float)hv[0] * wv[0] + (float)hv[1] * wv[1] +
                  (float)hv[2] * wv[2] + (float)hv[3] * wv[3];
#pragma unroll
        for (int m2 = 32; m2 >= 1; m2 >>= 1) s += __shfl_xor(s, m2, 64);
        float val = s + blin;
        ov = (lane == 63) ? val : ov;
        out[(size_t)(brow0 + w) * TN + 448 + lane] = ov;
    }
}

extern "C" void kernel_launch(void* const* d_in, const int* in_sizes, int n_in,
                              void* d_out, int out_size, void* d_ws, size_t ws_size,
                              hipStream_t stream) {
    const float* x     = (const float*)d_in[0];
    const float* W_ih  = (const float*)d_in[1];
    const float* W_hh  = (const float*)d_in[2];
    const float* b_ih  = (const float*)d_in[3];
    const float* b_hh  = (const float*)d_in[4];
    const float* W_lin = (const float*)d_in[5];
    const float* b_lin = (const float*)d_in[6];
    float* out = (float*)d_out;

    const size_t packBytes = (size_t)4 * HN * HN * sizeof(half_t);  // 512 KB
    if (ws_size >= packBytes) {
        half_t* W4 = (half_t*)d_ws;
        pack_w<<<(4 * HN * HN + 255) / 256, 256, 0, stream>>>(W_hh, W4);
        lstm_hot<true><<<NBLK, THREADS, 0, stream>>>(
            x, W_ih, W4, W_hh, b_ih, b_hh, W_lin, b_lin, out);
    } else {
        lstm_hot<false><<<NBLK, THREADS, 0, stream>>>(
            x, W_ih, nullptr, W_hh, b_ih, b_hh, W_lin, b_lin, out);
    }
}